// Round 4
// baseline (172.272 us; speedup 1.0000x reference)
//
#include <hip/hip_runtime.h>
#include <cstdint>
#include <cstddef>

// ManualChebConv: out[b,n,fo] = sum_k Zk[b] @ W[k] + bias
//   Z0 = x, Z1 = L@x, Zk = 2*L@Z_{k-1} - Z_{k-2}, K=5
// B=1024, N=512, F_in=16, F_out=8. L symmetric 512x512 fp32.
//
// R4: R3 was spill-bound (WRITE_SIZE 58 MB vs 16.8 ideal; VGPR cap = 128-64AGPR
// = 64 with 1024 thr). Changes:
//  - pipeline fits 64 VGPRs: B dbuf (32) + A depth-1 (16) as named vars,
//    wf fragments rebuilt per-epi (not live across kernel)
//  - LDS stride 520 -> 528 (8 dw mod 32: 16 bank start positions vs 8)
//  - acc-init trick: acc starts at -0.5*Z_{k-2} (prologue read, race-free:
//    per-lane element ownership), writeback stores 2*acc -> no RMW tail chain
// 1 block/CU (LDS 135 KB), 16 waves, mi=2 M-tiles/wave, ct=4.

typedef __attribute__((ext_vector_type(8))) short    frag_ab;  // 8 bf16
typedef __attribute__((ext_vector_type(4))) float    frag_cd;  // 4 fp32
typedef __attribute__((ext_vector_type(8))) uint16_t u16x8;

constexpr int BN    = 512;        // N
constexpr int FIN   = 16;
constexpr int FOUT  = 8;
constexpr int BT    = 4;          // batches per block
constexpr int NCOLS = BT * FIN;   // 64 combined cols
constexpr int LDST  = BN + 16;    // 528: stride = 264 dw = 8 mod 32
constexpr int ZBUF  = NCOLS * LDST;  // 33792 elements per buffer
constexpr int ZOFF  = 16;         // z1 offset: 8-bank shift

__device__ __forceinline__ uint16_t f2bf(float f) {
    uint32_t u = __builtin_bit_cast(uint32_t, f);
    u += 0x7FFFu + ((u >> 16) & 1u);          // round-to-nearest-even
    return (uint16_t)(u >> 16);
}
__device__ __forceinline__ float bf2f(uint16_t h) {
    uint32_t u = ((uint32_t)h) << 16;
    return __builtin_bit_cast(float, u);
}

__global__ void cvtL(const float* __restrict__ Lf, uint16_t* __restrict__ Lb) {
    int i = blockIdx.x * 256 + threadIdx.x;   // 128 blocks x 256 thr x 8 elems
    const float4* p = reinterpret_cast<const float4*>(Lf) + i * 2;
    float4 u0 = p[0], u1 = p[1];
    u16x8 o;
    o[0] = f2bf(u0.x); o[1] = f2bf(u0.y);
    o[2] = f2bf(u0.z); o[3] = f2bf(u0.w);
    o[4] = f2bf(u1.x); o[5] = f2bf(u1.y);
    o[6] = f2bf(u1.z); o[7] = f2bf(u1.w);
    *(reinterpret_cast<u16x8*>(Lb) + i) = o;
}

__global__ __launch_bounds__(1024, 1)
void cheb_kernel(const float* __restrict__ x, const uint16_t* __restrict__ Lb,
                 const float* __restrict__ W, const float* __restrict__ bvec,
                 float* __restrict__ out) {
    __shared__ uint16_t lds[2 * ZBUF + ZOFF];   // 135,200 B
    uint16_t* z0 = lds;
    uint16_t* z1 = lds + ZBUF + ZOFF;

    const int tid  = threadIdx.x;
    const int wave = tid >> 6;                // 0..15
    const int lane = tid & 63;
    const int lr   = lane & 15;               // A-row / B-col / D-col within tile
    const int q    = lane >> 4;               // quad

    // ---------------- stage x -> Z0^T (bf16) in z0 ----------------
    const float4* x4 = reinterpret_cast<const float4*>(x + (size_t)blockIdx.x * (BT * BN * FIN));
    {
        int a   = tid;                        // 1024 assignments, one each
        int f0g = a & 3;
        int n8  = (a >> 2) & 63;
        int bl  = a >> 8;
        int jb  = bl * 2048 + n8 * 32 + f0g;
        float4 v[8];
#pragma unroll
        for (int r = 0; r < 8; ++r) v[r] = x4[jb + r * 4];
        int cb = bl * 16 + f0g * 4;
        int nb = n8 * 8;
#pragma unroll
        for (int w = 0; w < 4; ++w) {
            frag_ab pk;
#pragma unroll
            for (int r = 0; r < 8; ++r)
                pk[r] = (short)f2bf(reinterpret_cast<const float*>(&v[r])[w]);
            *reinterpret_cast<frag_ab*>(&z0[(cb + w) * LDST + nb]) = pk;
        }
    }

    const float bv = (lr < 8) ? bvec[lr] : 0.0f;

    frag_cd accOut[2][4] = {};                // [mi][bt] out tiles (acc-class regs)

    // A-frag base: L[row = mt*16+lr][ks*32 + q*8], mt = wave + mi*16
    const uint16_t* aB0 = Lb + (wave * 16 + lr) * BN + q * 8;
    const uint16_t* aB1 = aB0 + 256 * BN;

    // One application. first: acc=0, store acc. else: acc=-0.5*Z_{k-2} (from
    // dst prologue read), store 2*acc. Element ownership is identical between
    // the prologue read and the writeback -> race-free without extra barrier.
    auto app = [&](const uint16_t* cur, uint16_t* dst, bool first) {
        frag_cd acc[2][4];
#pragma unroll
        for (int mi = 0; mi < 2; ++mi) {
            int row0 = (wave + mi * 16) * 16 + q * 4;
#pragma unroll
            for (int ct = 0; ct < 4; ++ct) {
                if (first) {
                    acc[mi][ct] = frag_cd{0.f, 0.f, 0.f, 0.f};
                } else {
                    const uint16_t* dp = dst + (ct * 16 + lr) * LDST + row0;
                    ushort4 pv = *reinterpret_cast<const ushort4*>(dp);
                    acc[mi][ct][0] = -0.5f * bf2f(pv.x);
                    acc[mi][ct][1] = -0.5f * bf2f(pv.y);
                    acc[mi][ct][2] = -0.5f * bf2f(pv.z);
                    acc[mi][ct][3] = -0.5f * bf2f(pv.w);
                }
            }
        }

        const uint16_t* bBase = cur + lr * LDST + q * 8;
        frag_ab bc0, bc1, bc2, bc3, bn0, bn1, bn2, bn3;
        frag_ab ac0, ac1, an0, an1;
        bc0 = *reinterpret_cast<const frag_ab*>(bBase + 0 * 16 * LDST);
        bc1 = *reinterpret_cast<const frag_ab*>(bBase + 1 * 16 * LDST);
        bc2 = *reinterpret_cast<const frag_ab*>(bBase + 2 * 16 * LDST);
        bc3 = *reinterpret_cast<const frag_ab*>(bBase + 3 * 16 * LDST);
        ac0 = *reinterpret_cast<const frag_ab*>(aB0);
        ac1 = *reinterpret_cast<const frag_ab*>(aB1);
#pragma unroll
        for (int ks = 0; ks < 16; ++ks) {
            if (ks < 15) {
                an0 = *reinterpret_cast<const frag_ab*>(aB0 + (ks + 1) * 32);
                an1 = *reinterpret_cast<const frag_ab*>(aB1 + (ks + 1) * 32);
                bn0 = *reinterpret_cast<const frag_ab*>(bBase + 0 * 16 * LDST + (ks + 1) * 32);
                bn1 = *reinterpret_cast<const frag_ab*>(bBase + 1 * 16 * LDST + (ks + 1) * 32);
                bn2 = *reinterpret_cast<const frag_ab*>(bBase + 2 * 16 * LDST + (ks + 1) * 32);
                bn3 = *reinterpret_cast<const frag_ab*>(bBase + 3 * 16 * LDST + (ks + 1) * 32);
            }
            acc[0][0] = __builtin_amdgcn_mfma_f32_16x16x32_bf16(ac0, bc0, acc[0][0], 0, 0, 0);
            acc[0][1] = __builtin_amdgcn_mfma_f32_16x16x32_bf16(ac0, bc1, acc[0][1], 0, 0, 0);
            acc[0][2] = __builtin_amdgcn_mfma_f32_16x16x32_bf16(ac0, bc2, acc[0][2], 0, 0, 0);
            acc[0][3] = __builtin_amdgcn_mfma_f32_16x16x32_bf16(ac0, bc3, acc[0][3], 0, 0, 0);
            acc[1][0] = __builtin_amdgcn_mfma_f32_16x16x32_bf16(ac1, bc0, acc[1][0], 0, 0, 0);
            acc[1][1] = __builtin_amdgcn_mfma_f32_16x16x32_bf16(ac1, bc1, acc[1][1], 0, 0, 0);
            acc[1][2] = __builtin_amdgcn_mfma_f32_16x16x32_bf16(ac1, bc2, acc[1][2], 0, 0, 0);
            acc[1][3] = __builtin_amdgcn_mfma_f32_16x16x32_bf16(ac1, bc3, acc[1][3], 0, 0, 0);
            if (ks < 15) {                    // rotate (renamed away under unroll)
                bc0 = bn0; bc1 = bn1; bc2 = bn2; bc3 = bn3;
                ac0 = an0; ac1 = an1;
            }
        }

        const float s = first ? 1.0f : 2.0f;
#pragma unroll
        for (int mi = 0; mi < 2; ++mi) {
            int row0 = (wave + mi * 16) * 16 + q * 4;
#pragma unroll
            for (int ct = 0; ct < 4; ++ct) {
                uint16_t* dp = dst + (ct * 16 + lr) * LDST + row0;
                ushort4 nv;
                nv.x = f2bf(s * acc[mi][ct][0]);
                nv.y = f2bf(s * acc[mi][ct][1]);
                nv.z = f2bf(s * acc[mi][ct][2]);
                nv.w = f2bf(s * acc[mi][ct][3]);
                *reinterpret_cast<ushort4*>(dp) = nv;
            }
        }
    };

    // Paired epilogue: accOut += [bufA | bufB](A-layout) @ W-pair p
    auto epi = [&](const uint16_t* bA, const uint16_t* bB, int p) {
        frag_ab wfr;                          // built here, not live across kernel
#pragma unroll
        for (int jj = 0; jj < 8; ++jj) {
            int k   = q * 8 + jj;
            int ki  = p * 2 + (k >> 4);
            int fin = k & 15;
            float val = (lr < 8 && ki < 5) ? W[ki * (FIN * FOUT) + fin * FOUT + lr] : 0.0f;
            wfr[jj] = (short)f2bf(val);
        }
        const uint16_t* base = (q < 2) ? bA : bB;
        int finb = (q & 1) * 8;
#pragma unroll
        for (int mi = 0; mi < 2; ++mi) {
            int n = (wave + mi * 16) * 16 + lr;
#pragma unroll
            for (int bt = 0; bt < 4; ++bt) {
                const uint16_t* pp = base + (bt * 16 + finb) * LDST + n;
                frag_ab afr;
#pragma unroll
                for (int jj = 0; jj < 8; ++jj) afr[jj] = (short)pp[jj * LDST];
                accOut[mi][bt] = __builtin_amdgcn_mfma_f32_16x16x32_bf16(
                    afr, wfr, accOut[mi][bt], 0, 0, 0);
            }
        }
    };

    __syncthreads();
    app(z0, z1, true);        // Z1 -> z1
    __syncthreads();
    epi(z0, z1, 0);           // out += Z0@W0 + Z1@W1
    __syncthreads();
    app(z1, z0, false);       // Z2 -> z0 (over Z0)
    __syncthreads();
    app(z0, z1, false);       // Z3 -> z1 (over Z1)
    __syncthreads();
    epi(z0, z1, 1);           // out += Z2@W2 + Z3@W3
    __syncthreads();
    app(z1, z0, false);       // Z4 -> z0 (over Z2)
    __syncthreads();
    epi(z0, z0, 2);           // out += Z4@W4 (second half weights zero)

    // ---------------- store ----------------
    if (lr < 8) {
        float* ob = out + (size_t)blockIdx.x * BT * BN * FOUT;
#pragma unroll
        for (int mi = 0; mi < 2; ++mi) {
            int row0 = (wave + mi * 16) * 16 + q * 4;
#pragma unroll
            for (int bt = 0; bt < 4; ++bt) {
                float* op = ob + bt * (BN * FOUT) + row0 * FOUT + lr;
                op[0 * FOUT] = accOut[mi][bt][0] + bv;
                op[1 * FOUT] = accOut[mi][bt][1] + bv;
                op[2 * FOUT] = accOut[mi][bt][2] + bv;
                op[3 * FOUT] = accOut[mi][bt][3] + bv;
            }
        }
    }
}

extern "C" void kernel_launch(void* const* d_in, const int* in_sizes, int n_in,
                              void* d_out, int out_size, void* d_ws, size_t ws_size,
                              hipStream_t stream) {
    const float* x  = (const float*)d_in[0];   // [1024,512,16]
    const float* Lf = (const float*)d_in[1];   // [512,512]
    const float* W  = (const float*)d_in[2];   // [5,16,8]
    const float* bv = (const float*)d_in[3];   // [8]
    float* out = (float*)d_out;                // [1024,512,8]

    uint16_t* Lb = (uint16_t*)d_ws;            // 512 KB bf16 copy of L
    cvtL<<<dim3(128), dim3(256), 0, stream>>>(Lf, Lb);
    cheb_kernel<<<dim3(256), dim3(1024), 0, stream>>>(x, Lb, W, bv, out);
}

// Round 5
// 159.862 us; speedup vs baseline: 1.0776x; 1.0776x over previous
//
#include <hip/hip_runtime.h>
#include <cstdint>
#include <cstddef>

// ManualChebConv: out[b,n,fo] = sum_k Zk[b] @ W[k] + bias
//   Z0 = x, Z1 = L@x, Zk = 2*L@Z_{k-1} - Z_{k-2}, K=5
// B=1024, N=512, F_in=16, F_out=8. L symmetric 512x512 fp32.
//
// R5: R4's explicit register pipeline SPILLED (WRITE_SIZE 102 MB vs 17 ideal;
// 128-reg/wave cap at 4 waves/SIMD, 64 AGPR acc leaves 64 VGPR, pipeline
// needed ~48 more). Fix: plain indexed loads in the fully-unrolled ks loop --
// loop-live ~40 VGPR, compiler schedules loads ahead within budget (R1 proved
// this structure spill-free; m97 shows compiler emits fine-grained lgkmcnt).
// Kept from R4: 1024 thr (16 waves, 4/SIMD), stride 528, acc-init trick
// (acc = -0.5*Z_{k-2} at prologue, store 2*acc -> no RMW tail), per-epi W
// rebuild. 1 block/CU (LDS 135 KB), mi=2 M-tiles/wave, ct=4.

typedef __attribute__((ext_vector_type(8))) short    frag_ab;  // 8 bf16
typedef __attribute__((ext_vector_type(4))) float    frag_cd;  // 4 fp32
typedef __attribute__((ext_vector_type(8))) uint16_t u16x8;

constexpr int BN    = 512;        // N
constexpr int FIN   = 16;
constexpr int FOUT  = 8;
constexpr int BT    = 4;          // batches per block
constexpr int NCOLS = BT * FIN;   // 64 combined cols
constexpr int LDST  = BN + 16;    // 528: stride = 264 dw = 8 mod 32
constexpr int ZBUF  = NCOLS * LDST;  // 33792 elements per buffer
constexpr int ZOFF  = 16;         // z1 offset: 8-bank shift

__device__ __forceinline__ uint16_t f2bf(float f) {
    uint32_t u = __builtin_bit_cast(uint32_t, f);
    u += 0x7FFFu + ((u >> 16) & 1u);          // round-to-nearest-even
    return (uint16_t)(u >> 16);
}
__device__ __forceinline__ float bf2f(uint16_t h) {
    uint32_t u = ((uint32_t)h) << 16;
    return __builtin_bit_cast(float, u);
}

__global__ void cvtL(const float* __restrict__ Lf, uint16_t* __restrict__ Lb) {
    int i = blockIdx.x * 256 + threadIdx.x;   // 128 blocks x 256 thr x 8 elems
    const float4* p = reinterpret_cast<const float4*>(Lf) + i * 2;
    float4 u0 = p[0], u1 = p[1];
    u16x8 o;
    o[0] = f2bf(u0.x); o[1] = f2bf(u0.y);
    o[2] = f2bf(u0.z); o[3] = f2bf(u0.w);
    o[4] = f2bf(u1.x); o[5] = f2bf(u1.y);
    o[6] = f2bf(u1.z); o[7] = f2bf(u1.w);
    *(reinterpret_cast<u16x8*>(Lb) + i) = o;
}

__global__ __launch_bounds__(1024, 1)
void cheb_kernel(const float* __restrict__ x, const uint16_t* __restrict__ Lb,
                 const float* __restrict__ W, const float* __restrict__ bvec,
                 float* __restrict__ out) {
    __shared__ uint16_t lds[2 * ZBUF + ZOFF];   // 135,200 B
    uint16_t* z0 = lds;
    uint16_t* z1 = lds + ZBUF + ZOFF;

    const int tid  = threadIdx.x;
    const int wave = tid >> 6;                // 0..15
    const int lane = tid & 63;
    const int lr   = lane & 15;               // A-row / B-col / D-col within tile
    const int q    = lane >> 4;               // quad

    // ---------------- stage x -> Z0^T (bf16) in z0 ----------------
    const float4* x4 = reinterpret_cast<const float4*>(x + (size_t)blockIdx.x * (BT * BN * FIN));
    {
        int a   = tid;                        // 1024 assignments, one each
        int f0g = a & 3;
        int n8  = (a >> 2) & 63;
        int bl  = a >> 8;
        int jb  = bl * 2048 + n8 * 32 + f0g;
        float4 v[8];
#pragma unroll
        for (int r = 0; r < 8; ++r) v[r] = x4[jb + r * 4];
        int cb = bl * 16 + f0g * 4;
        int nb = n8 * 8;
#pragma unroll
        for (int w = 0; w < 4; ++w) {
            frag_ab pk;
#pragma unroll
            for (int r = 0; r < 8; ++r)
                pk[r] = (short)f2bf(reinterpret_cast<const float*>(&v[r])[w]);
            *reinterpret_cast<frag_ab*>(&z0[(cb + w) * LDST + nb]) = pk;
        }
    }

    const float bv = (lr < 8) ? bvec[lr] : 0.0f;

    frag_cd accOut[2][4] = {};                // [mi][bt] out tiles (acc-class regs)

    // A-frag base: L[row = mt*16+lr][ks*32 + q*8], mt = wave + mi*16
    const uint16_t* aB0 = Lb + (wave * 16 + lr) * BN + q * 8;
    const uint16_t* aB1 = aB0 + 256 * BN;

    // One application. first: acc=0, store acc. else: acc=-0.5*Z_{k-2} (from
    // dst prologue read), store 2*acc. Element ownership is identical between
    // the prologue read and the writeback -> race-free without extra barrier.
    auto app = [&](const uint16_t* cur, uint16_t* dst, bool first) {
        frag_cd acc[2][4];
#pragma unroll
        for (int mi = 0; mi < 2; ++mi) {
            int row0 = (wave + mi * 16) * 16 + q * 4;
#pragma unroll
            for (int ct = 0; ct < 4; ++ct) {
                if (first) {
                    acc[mi][ct] = frag_cd{0.f, 0.f, 0.f, 0.f};
                } else {
                    const uint16_t* dp = dst + (ct * 16 + lr) * LDST + row0;
                    ushort4 pv = *reinterpret_cast<const ushort4*>(dp);
                    acc[mi][ct][0] = -0.5f * bf2f(pv.x);
                    acc[mi][ct][1] = -0.5f * bf2f(pv.y);
                    acc[mi][ct][2] = -0.5f * bf2f(pv.z);
                    acc[mi][ct][3] = -0.5f * bf2f(pv.w);
                }
            }
        }

        const uint16_t* bBase = cur + lr * LDST + q * 8;
#pragma unroll
        for (int ks = 0; ks < 16; ++ks) {
            // plain loads: compiler hoists ahead within the VGPR budget
            frag_ab b0 = *reinterpret_cast<const frag_ab*>(bBase + 0 * 16 * LDST + ks * 32);
            frag_ab b1 = *reinterpret_cast<const frag_ab*>(bBase + 1 * 16 * LDST + ks * 32);
            frag_ab b2 = *reinterpret_cast<const frag_ab*>(bBase + 2 * 16 * LDST + ks * 32);
            frag_ab b3 = *reinterpret_cast<const frag_ab*>(bBase + 3 * 16 * LDST + ks * 32);
            frag_ab a0 = *reinterpret_cast<const frag_ab*>(aB0 + ks * 32);
            frag_ab a1 = *reinterpret_cast<const frag_ab*>(aB1 + ks * 32);
            acc[0][0] = __builtin_amdgcn_mfma_f32_16x16x32_bf16(a0, b0, acc[0][0], 0, 0, 0);
            acc[0][1] = __builtin_amdgcn_mfma_f32_16x16x32_bf16(a0, b1, acc[0][1], 0, 0, 0);
            acc[0][2] = __builtin_amdgcn_mfma_f32_16x16x32_bf16(a0, b2, acc[0][2], 0, 0, 0);
            acc[0][3] = __builtin_amdgcn_mfma_f32_16x16x32_bf16(a0, b3, acc[0][3], 0, 0, 0);
            acc[1][0] = __builtin_amdgcn_mfma_f32_16x16x32_bf16(a1, b0, acc[1][0], 0, 0, 0);
            acc[1][1] = __builtin_amdgcn_mfma_f32_16x16x32_bf16(a1, b1, acc[1][1], 0, 0, 0);
            acc[1][2] = __builtin_amdgcn_mfma_f32_16x16x32_bf16(a1, b2, acc[1][2], 0, 0, 0);
            acc[1][3] = __builtin_amdgcn_mfma_f32_16x16x32_bf16(a1, b3, acc[1][3], 0, 0, 0);
        }

        const float s = first ? 1.0f : 2.0f;
#pragma unroll
        for (int mi = 0; mi < 2; ++mi) {
            int row0 = (wave + mi * 16) * 16 + q * 4;
#pragma unroll
            for (int ct = 0; ct < 4; ++ct) {
                uint16_t* dp = dst + (ct * 16 + lr) * LDST + row0;
                ushort4 nv;
                nv.x = f2bf(s * acc[mi][ct][0]);
                nv.y = f2bf(s * acc[mi][ct][1]);
                nv.z = f2bf(s * acc[mi][ct][2]);
                nv.w = f2bf(s * acc[mi][ct][3]);
                *reinterpret_cast<ushort4*>(dp) = nv;
            }
        }
    };

    // Paired epilogue: accOut += [bufA | bufB](A-layout) @ W-pair p
    auto epi = [&](const uint16_t* bA, const uint16_t* bB, int p) {
        frag_ab wfr;                          // built here, not live across kernel
#pragma unroll
        for (int jj = 0; jj < 8; ++jj) {
            int k   = q * 8 + jj;
            int ki  = p * 2 + (k >> 4);
            int fin = k & 15;
            float val = (lr < 8 && ki < 5) ? W[ki * (FIN * FOUT) + fin * FOUT + lr] : 0.0f;
            wfr[jj] = (short)f2bf(val);
        }
        const uint16_t* base = (q < 2) ? bA : bB;
        int finb = (q & 1) * 8;
#pragma unroll
        for (int mi = 0; mi < 2; ++mi) {
            int n = (wave + mi * 16) * 16 + lr;
#pragma unroll
            for (int bt = 0; bt < 4; ++bt) {
                const uint16_t* pp = base + (bt * 16 + finb) * LDST + n;
                frag_ab afr;
#pragma unroll
                for (int jj = 0; jj < 8; ++jj) afr[jj] = (short)pp[jj * LDST];
                accOut[mi][bt] = __builtin_amdgcn_mfma_f32_16x16x32_bf16(
                    afr, wfr, accOut[mi][bt], 0, 0, 0);
            }
        }
    };

    __syncthreads();
    app(z0, z1, true);        // Z1 -> z1
    __syncthreads();
    epi(z0, z1, 0);           // out += Z0@W0 + Z1@W1
    __syncthreads();
    app(z1, z0, false);       // Z2 -> z0 (over Z0)
    __syncthreads();
    app(z0, z1, false);       // Z3 -> z1 (over Z1)
    __syncthreads();
    epi(z0, z1, 1);           // out += Z2@W2 + Z3@W3
    __syncthreads();
    app(z1, z0, false);       // Z4 -> z0 (over Z2)
    __syncthreads();
    epi(z0, z0, 2);           // out += Z4@W4 (second half weights zero)

    // ---------------- store ----------------
    if (lr < 8) {
        float* ob = out + (size_t)blockIdx.x * BT * BN * FOUT;
#pragma unroll
        for (int mi = 0; mi < 2; ++mi) {
            int row0 = (wave + mi * 16) * 16 + q * 4;
#pragma unroll
            for (int bt = 0; bt < 4; ++bt) {
                float* op = ob + bt * (BN * FOUT) + row0 * FOUT + lr;
                op[0 * FOUT] = accOut[mi][bt][0] + bv;
                op[1 * FOUT] = accOut[mi][bt][1] + bv;
                op[2 * FOUT] = accOut[mi][bt][2] + bv;
                op[3 * FOUT] = accOut[mi][bt][3] + bv;
            }
        }
    }
}

extern "C" void kernel_launch(void* const* d_in, const int* in_sizes, int n_in,
                              void* d_out, int out_size, void* d_ws, size_t ws_size,
                              hipStream_t stream) {
    const float* x  = (const float*)d_in[0];   // [1024,512,16]
    const float* Lf = (const float*)d_in[1];   // [512,512]
    const float* W  = (const float*)d_in[2];   // [5,16,8]
    const float* bv = (const float*)d_in[3];   // [8]
    float* out = (float*)d_out;                // [1024,512,8]

    uint16_t* Lb = (uint16_t*)d_ws;            // 512 KB bf16 copy of L
    cvtL<<<dim3(128), dim3(256), 0, stream>>>(Lf, Lb);
    cheb_kernel<<<dim3(256), dim3(1024), 0, stream>>>(x, Lb, W, bv, out);
}